// Round 3
// baseline (69.928 us; speedup 1.0000x reference)
//
#include <hip/hip_runtime.h>
#include <math.h>

#define NQ 10
#define NL 4

// out[i,h] = cos(x_ih)*<v|Z_h|v> - sin(x_ih)*<v|X_h|v> for h<10, else 0,
// where v is the (token-independent) state after the 4 shared layers.
// Wave 0 of every block simulates v in registers (16 amps/lane; s-bits[9:4]=lane,
// [3:0]=reg); CNOT ring = cndmask + ds_bpermute (XOR-linear factorization);
// all other threads pre-compute their x-trig before the barrier.
__global__ __launch_bounds__(256) void qc_fused(const float* __restrict__ x,
                                                const float* __restrict__ params,
                                                float* __restrict__ out) {
    __shared__ float csc[NL * NQ];
    __shared__ float css[NL * NQ];
    __shared__ __align__(16) float red[20][68];   // padded rows: conflict-free
    __shared__ float sAB[20];                     // A_0..9, B_0..9

    const int tid = threadIdx.x;
    const int i = blockIdx.x * 256 + tid;
    const int h0 = (i << 2) & 63;                 // feature of component .x
    const bool act = (h0 < 12);                   // h0 in {0,4,8}

    // Phase 0 (all threads): x load + fast trig, independent of the sim.
    float c0 = 0.f, s0 = 0.f, c1 = 0.f, s1 = 0.f;
    float c2 = 0.f, s2 = 0.f, c3 = 0.f, s3 = 0.f;
    if (act) {
        const float4 xv = reinterpret_cast<const float4*>(x)[i];
        __sincosf(xv.x, &s0, &c0);
        __sincosf(xv.y, &s1, &c1);
        if (h0 + 2 < NQ) {                        // h0==8 -> z,w are h=10,11 -> 0
            __sincosf(xv.z, &s2, &c2);
            __sincosf(xv.w, &s3, &c3);
        }
    }

    // Phase 1 (wave 0): simulate the shared circuit.
    if (tid < 64) {
        const int lane = tid;
        if (lane < NL * NQ) {
            float sv, cv;
            __sincosf(0.5f * params[lane], &sv, &cv);
            csc[lane] = cv;
            css[lane] = sv;
        }

        // sigma (CNOT ring, gather form): b9'=b9^b0, bk'=bk^b(k+1) k=0..7, b8'=b8^b9^b0.
        // reg part:  src_reg  = g(r) ^ (parity(src_lane) << 3), g(r)=((r^(r>>1))&7)|(r&8)
        // lane part: src_lane = lam(l) ^ (r&1 ? 48 : 0),        lam(l)=((l^(l>>1))&31)|(l&32)
        const int lam = ((lane ^ (lane >> 1)) & 31) | (lane & 32);
        const int addr_even = lam << 2;
        const int addr_odd  = (lam ^ 48) << 2;
        const int par = __builtin_popcount(lane) & 1;

        float v[16];
#pragma unroll
        for (int r = 0; r < 16; ++r) v[r] = 0.0f;
        if (lane == 0) v[0] = 1.0f;

        __asm__ volatile("s_waitcnt lgkmcnt(0)" ::: "memory");  // csc/css visible (wave-private)

#pragma unroll
        for (int l = 0; l < NL; ++l) {
            // RY on lane-bit qubits q=0..5 (s-bit 9-q = lane-bit 5-q)
#pragma unroll
            for (int q = 0; q < 6; ++q) {
                const float c = csc[l * NQ + q];
                const float s = css[l * NQ + q];
                const float t = ((lane >> (5 - q)) & 1) ? s : -s;
#pragma unroll
                for (int r = 0; r < 16; ++r) {
                    const float p = __shfl_xor(v[r], 1 << (5 - q), 64);
                    v[r] = fmaf(t, p, c * v[r]);
                }
            }
            // RY on register-bit qubits q=6..9
#pragma unroll
            for (int q = 6; q < NQ; ++q) {
                const float c = csc[l * NQ + q];
                const float s = css[l * NQ + q];
                const int mr = 1 << (9 - q);
#pragma unroll
                for (int r = 0; r < 16; ++r) {
                    if (!(r & mr)) {
                        const float v0 = v[r], v1 = v[r | mr];
                        v[r]      = fmaf(-s, v1, c * v0);
                        v[r | mr] = fmaf( s, v0, c * v1);
                    }
                }
            }
            // CNOT ring via register remap + bpermute (no LDS staging).
            float nv[16];
#pragma unroll
            for (int r = 0; r < 16; ++r) {
                const int gsrc = ((r ^ (r >> 1)) & 7) | (r & 8);
                const float u = par ? v[gsrc ^ 8] : v[gsrc];
                nv[r] = __int_as_float(__builtin_amdgcn_ds_bpermute(
                    (r & 1) ? addr_odd : addr_even, __float_as_int(u)));
            }
#pragma unroll
            for (int r = 0; r < 16; ++r) v[r] = nv[r];
        }

        // Per-lane partials: A_q = sum +-v^2, B_q = sum v_s*v_{s^m}
        float E = 0.0f;
#pragma unroll
        for (int r = 0; r < 16; ++r) E = fmaf(v[r], v[r], E);

#pragma unroll
        for (int q = 0; q < 6; ++q) {
            const int m = 1 << (5 - q);
            float b = 0.0f, b2 = 0.0f;
#pragma unroll
            for (int r = 0; r < 16; ++r) {
                const float p = __shfl_xor(v[r], m, 64);
                if (r & 1) b2 = fmaf(v[r], p, b2);
                else       b  = fmaf(v[r], p, b);
            }
            red[q][lane]      = ((lane >> (5 - q)) & 1) ? -E : E;
            red[10 + q][lane] = b + b2;
        }
#pragma unroll
        for (int q = 6; q < NQ; ++q) {
            const int mr = 1 << (9 - q);
            float a = 0.0f, b = 0.0f;
#pragma unroll
            for (int r = 0; r < 16; ++r) {
                a += ((r & mr) ? -1.0f : 1.0f) * v[r] * v[r];
                b = fmaf(v[r], v[r ^ mr], b);
            }
            red[q][lane]      = a;
            red[10 + q][lane] = b;
        }
        __asm__ volatile("s_waitcnt lgkmcnt(0)" ::: "memory");

        // Row sums: 20 lanes, one latency round-trip, float4 reads (rows 16B-aligned).
        if (lane < 20) {
            const float4* row = reinterpret_cast<const float4*>(&red[lane][0]);
            float4 a = row[0], b = row[1];
#pragma unroll
            for (int j = 2; j < 16; j += 2) {
                const float4 ra = row[j], rb = row[j + 1];
                a.x += ra.x; a.y += ra.y; a.z += ra.z; a.w += ra.w;
                b.x += rb.x; b.y += rb.y; b.z += rb.z; b.w += rb.w;
            }
            sAB[lane] = (a.x + a.y) + (a.z + a.w) + (b.x + b.y) + (b.z + b.w);
        }
    }
    __syncthreads();

    // Phase 2: two FMAs per component + store.
    float4 o = make_float4(0.f, 0.f, 0.f, 0.f);
    if (act) {
        o.x = c0 * sAB[h0]     - s0 * sAB[10 + h0];
        o.y = c1 * sAB[h0 + 1] - s1 * sAB[10 + h0 + 1];
        if (h0 + 2 < NQ) {
            o.z = c2 * sAB[h0 + 2] - s2 * sAB[10 + h0 + 2];
            o.w = c3 * sAB[h0 + 3] - s3 * sAB[10 + h0 + 3];
        }
    }
    reinterpret_cast<float4*>(out)[i] = o;
}

extern "C" void kernel_launch(void* const* d_in, const int* in_sizes, int n_in,
                              void* d_out, int out_size, void* d_ws, size_t ws_size,
                              hipStream_t stream) {
    const float* x      = (const float*)d_in[0];   // (4,1024,64) f32
    const float* params = (const float*)d_in[1];   // (4,10) f32
    float* out = (float*)d_out;                    // (4,1024,64) f32

    const int total4 = out_size / 4;               // 65536 float4s
    qc_fused<<<total4 / 256, 256, 0, stream>>>(x, params, out);
}

// Round 4
// 58.701 us; speedup vs baseline: 1.1913x; 1.1913x over previous
//
#include <hip/hip_runtime.h>
#include <math.h>

#define NQ 10
#define NL 4

// out[i,h] = cos(x_ih)*<v|Z_h|v> - sin(x_ih)*<v|X_h|v> for h<10, else 0,
// where v = state after the 4 shared (token-independent) layers.
// Cooperative 4-wave sim: 1024 amps = 256 threads x 4 regs.
// s-bits: [9:8]=wave (qubits 0,1), [7:2]=lane (qubits 2..7), [1:0]=reg (8,9).
// Wave-bit RY pair fused into one 4x4 matrix (one LDS round trip / layer);
// CNOT ring = one composed-permutation LDS gather / layer.
__global__ __launch_bounds__(256) void qc_fused(const float* __restrict__ x,
                                                const float* __restrict__ params,
                                                float* __restrict__ out) {
    __shared__ float csc[NL * NQ];
    __shared__ float css[NL * NQ];
    __shared__ __align__(16) float bufA[1024];
    __shared__ __align__(16) float bufB[1024];
    __shared__ __align__(16) float red[20][260];   // padded rows, 16B-aligned
    __shared__ float red2[20][4];
    __shared__ float sAB[20];                      // A_0..9, B_0..9

    const int tid  = threadIdx.x;
    const int w    = tid >> 6;
    const int lane = tid & 63;

    // Phase 0 (all threads): x load + fast trig — independent of the sim,
    // overlaps it.
    const int i  = blockIdx.x * 256 + tid;
    const int h0 = (i << 2) & 63;
    const bool act = (h0 < 12);                    // h0 in {0,4,8}
    float c0 = 0, s0 = 0, c1 = 0, s1 = 0, c2 = 0, s2 = 0, c3 = 0, s3 = 0;
    if (act) {
        const float4 xv = reinterpret_cast<const float4*>(x)[i];
        __sincosf(xv.x, &s0, &c0);
        __sincosf(xv.y, &s1, &c1);
        if (h0 + 2 < NQ) {
            __sincosf(xv.z, &s2, &c2);
            __sincosf(xv.w, &s3, &c3);
        }
    }

    // Gate trig (visible after the first in-layer barrier).
    if (tid < NL * NQ) {
        float sv, cv;
        __sincosf(0.5f * params[tid], &sv, &cv);
        csc[tid] = cv;
        css[tid] = sv;
    }

    // Composed CNOT-ring permutation sources (gather form), one per reg.
    int src[4];
#pragma unroll
    for (int r = 0; r < 4; ++r) {
        int t = (tid << 2) | r;
        t ^= (t & 1) << 9;                         // CNOT(9,0) contribution
#pragma unroll
        for (int j = 8; j >= 0; --j)               // CNOT(j,j+1)
            t ^= ((t >> (9 - j)) & 1) << (8 - j);
        src[r] = t;
    }

    float v[4] = {0.f, 0.f, 0.f, 0.f};
    if (tid == 0) v[0] = 1.0f;

    float4* bufA4 = reinterpret_cast<float4*>(bufA);
    float4* bufB4 = reinterpret_cast<float4*>(bufB);

#pragma unroll
    for (int l = 0; l < NL; ++l) {
        // --- qubits 0,1 (wave bits): fused 4x4 = RY(th0) (x) RY(th1) ---
        bufA4[tid] = make_float4(v[0], v[1], v[2], v[3]);
        __syncthreads();
        {
            const float cq0 = csc[l * NQ + 0], sq0 = css[l * NQ + 0];
            const float cq1 = csc[l * NQ + 1], sq1 = css[l * NQ + 1];
            const int a = w >> 1, b = w & 1;       // my (qubit0, qubit1) bits
            float m[4];
#pragma unroll
            for (int wp = 0; wp < 4; ++wp) {       // source wave
                const int ap = wp >> 1, bp = wp & 1;
                const float e0 = (a == ap) ? cq0 : ((ap > a) ? -sq0 : sq0);
                const float e1 = (b == bp) ? cq1 : ((bp > b) ? -sq1 : sq1);
                m[wp] = e0 * e1;
            }
            const float4 u0 = bufA4[lane];
            const float4 u1 = bufA4[64 + lane];
            const float4 u2 = bufA4[128 + lane];
            const float4 u3 = bufA4[192 + lane];
            v[0] = m[0] * u0.x + m[1] * u1.x + m[2] * u2.x + m[3] * u3.x;
            v[1] = m[0] * u0.y + m[1] * u1.y + m[2] * u2.y + m[3] * u3.y;
            v[2] = m[0] * u0.z + m[1] * u1.z + m[2] * u2.z + m[3] * u3.z;
            v[3] = m[0] * u0.w + m[1] * u1.w + m[2] * u2.w + m[3] * u3.w;
        }
        // --- qubits 2..7 (lane bits): shfl_xor, 4 ops/stage ---
#pragma unroll
        for (int q = 2; q < 8; ++q) {
            const float c = csc[l * NQ + q], s = css[l * NQ + q];
            const int bit = 1 << (7 - q);
            const float t = (lane & bit) ? s : -s;
#pragma unroll
            for (int r = 0; r < 4; ++r) {
                const float p = __shfl_xor(v[r], bit, 64);
                v[r] = fmaf(t, p, c * v[r]);
            }
        }
        // --- qubits 8,9 (reg bits): in-register ---
        {
            const float c8 = csc[l * NQ + 8], s8 = css[l * NQ + 8];
            const float n0 = fmaf(-s8, v[2], c8 * v[0]);
            const float n2 = fmaf( s8, v[0], c8 * v[2]);
            const float n1 = fmaf(-s8, v[3], c8 * v[1]);
            const float n3 = fmaf( s8, v[1], c8 * v[3]);
            const float c9 = csc[l * NQ + 9], s9 = css[l * NQ + 9];
            v[0] = fmaf(-s9, n1, c9 * n0);
            v[1] = fmaf( s9, n0, c9 * n1);
            v[2] = fmaf(-s9, n3, c9 * n2);
            v[3] = fmaf( s9, n2, c9 * n3);
        }
        // --- CNOT ring: one LDS gather (double-buffered vs stage 1) ---
        bufB4[tid] = make_float4(v[0], v[1], v[2], v[3]);
        __syncthreads();
#pragma unroll
        for (int r = 0; r < 4; ++r) v[r] = bufB[src[r]];
    }

    // Final state to LDS for the cross-wave (qubit 0,1) X-partials.
    bufA4[tid] = make_float4(v[0], v[1], v[2], v[3]);
    __syncthreads();
    const float4 p0 = bufA4[((w ^ 2) << 6) | lane];   // qubit0 partner (bit9)
    const float4 p1 = bufA4[((w ^ 1) << 6) | lane];   // qubit1 partner (bit8)

    // Per-thread partials: A_q = sum +-v^2, B_q = sum v_s*v_{s^m}.
    const float E = v[0] * v[0] + v[1] * v[1] + v[2] * v[2] + v[3] * v[3];
    float pA[NQ], pB[NQ];
    pA[0] = (w & 2) ? -E : E;
    pA[1] = (w & 1) ? -E : E;
    pB[0] = v[0] * p0.x + v[1] * p0.y + v[2] * p0.z + v[3] * p0.w;
    pB[1] = v[0] * p1.x + v[1] * p1.y + v[2] * p1.z + v[3] * p1.w;
#pragma unroll
    for (int q = 2; q < 8; ++q) {
        const int bit = 1 << (7 - q);
        pA[q] = (lane & bit) ? -E : E;
        float b = 0.0f;
#pragma unroll
        for (int r = 0; r < 4; ++r)
            b = fmaf(v[r], __shfl_xor(v[r], bit, 64), b);
        pB[q] = b;
    }
    pA[8] = v[0] * v[0] + v[1] * v[1] - v[2] * v[2] - v[3] * v[3];
    pB[8] = 2.0f * (v[0] * v[2] + v[1] * v[3]);
    pA[9] = v[0] * v[0] - v[1] * v[1] + v[2] * v[2] - v[3] * v[3];
    pB[9] = 2.0f * (v[0] * v[1] + v[2] * v[3]);

    // Global reduction: rows -> quarter-row float4 sums -> final 20.
#pragma unroll
    for (int q = 0; q < NQ; ++q) {
        red[q][tid]      = pA[q];
        red[10 + q][tid] = pB[q];
    }
    __syncthreads();
    if (tid < 80) {
        const int q = tid >> 2, seg = tid & 3;
        const float4* row = reinterpret_cast<const float4*>(&red[q][seg * 64]);
        float4 a = row[0];
#pragma unroll
        for (int j = 1; j < 16; ++j) {
            const float4 t = row[j];
            a.x += t.x; a.y += t.y; a.z += t.z; a.w += t.w;
        }
        red2[q][seg] = (a.x + a.y) + (a.z + a.w);
    }
    __syncthreads();
    if (tid < 20)
        sAB[tid] = (red2[tid][0] + red2[tid][1]) + (red2[tid][2] + red2[tid][3]);
    __syncthreads();

    // Phase 2: two FMAs per component + float4 store.
    float4 o = make_float4(0.f, 0.f, 0.f, 0.f);
    if (act) {
        o.x = c0 * sAB[h0]     - s0 * sAB[10 + h0];
        o.y = c1 * sAB[h0 + 1] - s1 * sAB[10 + h0 + 1];
        if (h0 + 2 < NQ) {
            o.z = c2 * sAB[h0 + 2] - s2 * sAB[10 + h0 + 2];
            o.w = c3 * sAB[h0 + 3] - s3 * sAB[10 + h0 + 3];
        }
    }
    reinterpret_cast<float4*>(out)[i] = o;
}

extern "C" void kernel_launch(void* const* d_in, const int* in_sizes, int n_in,
                              void* d_out, int out_size, void* d_ws, size_t ws_size,
                              hipStream_t stream) {
    const float* x      = (const float*)d_in[0];   // (4,1024,64) f32
    const float* params = (const float*)d_in[1];   // (4,10) f32
    float* out = (float*)d_out;                    // (4,1024,64) f32

    const int total4 = out_size / 4;               // 65536 float4s
    qc_fused<<<total4 / 256, 256, 0, stream>>>(x, params, out);
}

// Round 5
// 57.350 us; speedup vs baseline: 1.2193x; 1.0236x over previous
//
#include <hip/hip_runtime.h>
#include <math.h>

#define NQ 10
#define NL 4

// CNOT-ring gather permutation: new[s] = old[sigma(s)]. XOR-linear, so
// sigma(a^b)=sigma(a)^sigma(b); called with constants it folds at compile time.
__host__ __device__ constexpr int csigma(int t) {
    t ^= (t & 1) << 9;                              // CNOT(9,0)
    for (int j = 8; j >= 0; --j)                    // CNOT(j,j+1)
        t ^= ((t >> (9 - j)) & 1) << (8 - j);
    return t;
}

// out[i,h] = cos(x_ih)*<v|Z_h|v> - sin(x_ih)*<v|X_h|v> (h<10; else 0),
// v = state after 4 shared layers. 1024 amps = 256 threads x 4 regs.
// s-bits: [9:8]=wave (qubits 0,1), [7:2]=lane (2..7), [1:0]=reg (8,9).
// Layer 0 = direct product state (no comm). Each later layer: ONE LDS
// round-trip (wave 4x4 with the previous CNOT ring composed into the read
// addresses) + 3 fused lane-pair 4x4 shfl stages + in-register qubits 8,9.
__global__ __launch_bounds__(256) void qc_fused(const float* __restrict__ x,
                                                const float* __restrict__ params,
                                                float* __restrict__ out) {
    __shared__ float csc[NL * NQ];
    __shared__ float css[NL * NQ];
    __shared__ __align__(16) float bufA[1024];
    __shared__ __align__(16) float bufB[1024];
    __shared__ __align__(16) float red[20][260];    // rows 16B-aligned
    __shared__ float red2[20][4];
    __shared__ float sAB[20];

    const int tid  = threadIdx.x;
    const int w    = tid >> 6;
    const int lane = tid & 63;

    // ---- Phase 0 (all threads): x trig, independent of the sim ----
    const int i  = blockIdx.x * 256 + tid;
    const int h0 = (i << 2) & 63;
    const bool act = (h0 < 12);                     // h0 in {0,4,8}
    float c0 = 0, s0 = 0, c1 = 0, s1 = 0, c2 = 0, s2 = 0, c3 = 0, s3 = 0;
    if (act) {
        const float4 xv = reinterpret_cast<const float4*>(x)[i];
        __sincosf(xv.x, &s0, &c0);
        __sincosf(xv.y, &s1, &c1);
        if (h0 + 2 < NQ) {
            __sincosf(xv.z, &s2, &c2);
            __sincosf(xv.w, &s3, &c3);
        }
    }

    // ---- Gate trig ----
    if (tid < NL * NQ) {
        float sv, cv;
        __sincosf(0.5f * params[tid], &sv, &cv);
        csc[tid] = cv;
        css[tid] = sv;
    }
    __syncthreads();

    // Prefetch all gate coefficients into registers (off the chain thereafter).
    float C[NL * NQ], S[NL * NQ];
#pragma unroll
    for (int j = 0; j < NL * NQ / 4; ++j) {
        reinterpret_cast<float4*>(C)[j] = reinterpret_cast<const float4*>(csc)[j];
        reinterpret_cast<float4*>(S)[j] = reinterpret_cast<const float4*>(css)[j];
    }

    // ---- Layer 0: product state, no communication ----
    float v[4];
    {
        float p = 1.0f;
#pragma unroll
        for (int q = 0; q < 8; ++q)                 // qubit q <-> tid bit 7-q
            p *= ((tid >> (7 - q)) & 1) ? S[q] : C[q];
        const float p8c = p * C[8], p8s = p * S[8];
        v[0] = p8c * C[9]; v[1] = p8c * S[9];
        v[2] = p8s * C[9]; v[3] = p8s * S[9];
    }
    reinterpret_cast<float4*>(bufA)[tid] = make_float4(v[0], v[1], v[2], v[3]);
    __syncthreads();

    const int sig_lane = csigma(lane << 2);         // runtime part of sigma

    // ---- Layers 1..3 ----
#pragma unroll
    for (int l = 1; l < NL; ++l) {
        const float* src = (l & 1) ? bufA : bufB;   // l1:A->B, l2:B->A, l3:A->B
        float* dst = (l & 1) ? bufB : bufA;

        // Wave-bit 4x4 (qubits 0,1) with previous CNOT ring composed in.
        const float cq0 = C[l * NQ + 0], sq0 = S[l * NQ + 0];
        const float cq1 = C[l * NQ + 1], sq1 = S[l * NQ + 1];
        const int a = w >> 1, b = w & 1;
        float m[4];
#pragma unroll
        for (int wp = 0; wp < 4; ++wp) {
            const int ap = wp >> 1, bp = wp & 1;
            const float e0 = (a == ap) ? cq0 : ((ap > a) ? -sq0 : sq0);
            const float e1 = (b == bp) ? cq1 : ((bp > b) ? -sq1 : sq1);
            m[wp] = e0 * e1;
        }
        float u[4][4];
#pragma unroll
        for (int wp = 0; wp < 4; ++wp)
#pragma unroll
            for (int r = 0; r < 4; ++r)
                u[wp][r] = src[sig_lane ^ csigma((wp << 8) | r)];
#pragma unroll
        for (int r = 0; r < 4; ++r)
            v[r] = fmaf(m[3], u[3][r], fmaf(m[2], u[2][r],
                   fmaf(m[1], u[1][r], m[0] * u[0][r])));

        // Lane-bit qubits fused in pairs: (2,3),(4,5),(6,7) -> 3 shfl levels.
#pragma unroll
        for (int pr = 0; pr < 3; ++pr) {
            const int qa = 2 + 2 * pr, qb = qa + 1;
            const int ma = 1 << (7 - qa), mb = 1 << (7 - qb);
            const float ca = C[l * NQ + qa], sa = S[l * NQ + qa];
            const float cb = C[l * NQ + qb], sb = S[l * NQ + qb];
            const float ea = (lane & ma) ? sa : -sa;
            const float eb = (lane & mb) ? sb : -sb;
            const float kaa = ca * cb, kab = ca * eb, kba = ea * cb, kbb = ea * eb;
#pragma unroll
            for (int r = 0; r < 4; ++r) {
                const float pa  = __shfl_xor(v[r], ma, 64);
                const float pb  = __shfl_xor(v[r], mb, 64);
                const float pab = __shfl_xor(v[r], ma | mb, 64);
                v[r] = fmaf(kbb, pab, fmaf(kba, pa, fmaf(kab, pb, kaa * v[r])));
            }
        }

        // Reg-bit qubits 8,9 in-register.
        {
            const float c8 = C[l * NQ + 8], s8 = S[l * NQ + 8];
            const float n0 = fmaf(-s8, v[2], c8 * v[0]);
            const float n2 = fmaf( s8, v[0], c8 * v[2]);
            const float n1 = fmaf(-s8, v[3], c8 * v[1]);
            const float n3 = fmaf( s8, v[1], c8 * v[3]);
            const float c9 = C[l * NQ + 9], s9 = S[l * NQ + 9];
            v[0] = fmaf(-s9, n1, c9 * n0);
            v[1] = fmaf( s9, n0, c9 * n1);
            v[2] = fmaf(-s9, n3, c9 * n2);
            v[3] = fmaf( s9, n2, c9 * n3);
        }
        reinterpret_cast<float4*>(dst)[tid] = make_float4(v[0], v[1], v[2], v[3]);
        __syncthreads();
    }

    // ---- Final CNOT ring composed into the reduction gather (bufB holds y3) ----
    const int sig_tid = sig_lane ^ csigma(w << 8);
    float p0[4], p1[4];
#pragma unroll
    for (int r = 0; r < 4; ++r) {
        v[r]  = bufB[sig_tid ^ csigma(r)];
        p0[r] = bufB[sig_tid ^ csigma(512 | r)];    // qubit-0 partner (bit 9)
        p1[r] = bufB[sig_tid ^ csigma(256 | r)];    // qubit-1 partner (bit 8)
    }

    // ---- Per-thread partials: A_q = sum +-v^2, B_q = sum v_s*v_{s^m} ----
    const float E = v[0] * v[0] + v[1] * v[1] + v[2] * v[2] + v[3] * v[3];
    float pA[NQ], pB[NQ];
    pA[0] = (w & 2) ? -E : E;
    pA[1] = (w & 1) ? -E : E;
    pB[0] = v[0] * p0[0] + v[1] * p0[1] + v[2] * p0[2] + v[3] * p0[3];
    pB[1] = v[0] * p1[0] + v[1] * p1[1] + v[2] * p1[2] + v[3] * p1[3];
#pragma unroll
    for (int q = 2; q < 8; ++q) {                   // independent shfls: pipeline
        const int bit = 1 << (7 - q);
        pA[q] = (lane & bit) ? -E : E;
        float bsum = 0.0f;
#pragma unroll
        for (int r = 0; r < 4; ++r)
            bsum = fmaf(v[r], __shfl_xor(v[r], bit, 64), bsum);
        pB[q] = bsum;
    }
    pA[8] = v[0] * v[0] + v[1] * v[1] - v[2] * v[2] - v[3] * v[3];
    pB[8] = 2.0f * (v[0] * v[2] + v[1] * v[3]);
    pA[9] = v[0] * v[0] - v[1] * v[1] + v[2] * v[2] - v[3] * v[3];
    pB[9] = 2.0f * (v[0] * v[1] + v[2] * v[3]);

    // ---- Block reduction: rows -> quarter-row float4 sums -> final 20 ----
#pragma unroll
    for (int q = 0; q < NQ; ++q) {
        red[q][tid]      = pA[q];
        red[10 + q][tid] = pB[q];
    }
    __syncthreads();
    if (tid < 80) {
        const int q = tid >> 2, seg = tid & 3;
        const float4* row = reinterpret_cast<const float4*>(&red[q][seg * 64]);
        float4 a0 = row[0], a1 = row[1], a2 = row[2], a3 = row[3];
#pragma unroll
        for (int j = 4; j < 16; j += 4) {
            const float4 t0 = row[j], t1 = row[j + 1], t2 = row[j + 2], t3 = row[j + 3];
            a0.x += t0.x; a0.y += t0.y; a0.z += t0.z; a0.w += t0.w;
            a1.x += t1.x; a1.y += t1.y; a1.z += t1.z; a1.w += t1.w;
            a2.x += t2.x; a2.y += t2.y; a2.z += t2.z; a2.w += t2.w;
            a3.x += t3.x; a3.y += t3.y; a3.z += t3.z; a3.w += t3.w;
        }
        a0.x += a1.x; a0.y += a1.y; a0.z += a1.z; a0.w += a1.w;
        a2.x += a3.x; a2.y += a3.y; a2.z += a3.z; a2.w += a3.w;
        red2[q][seg] = (a0.x + a0.y) + (a0.z + a0.w) + (a2.x + a2.y) + (a2.z + a2.w);
    }
    __syncthreads();
    if (tid < 20)
        sAB[tid] = (red2[tid][0] + red2[tid][1]) + (red2[tid][2] + red2[tid][3]);
    __syncthreads();

    // ---- Phase 2: two FMAs per component + float4 store ----
    float4 o = make_float4(0.f, 0.f, 0.f, 0.f);
    if (act) {
        o.x = c0 * sAB[h0]     - s0 * sAB[10 + h0];
        o.y = c1 * sAB[h0 + 1] - s1 * sAB[10 + h0 + 1];
        if (h0 + 2 < NQ) {
            o.z = c2 * sAB[h0 + 2] - s2 * sAB[10 + h0 + 2];
            o.w = c3 * sAB[h0 + 3] - s3 * sAB[10 + h0 + 3];
        }
    }
    reinterpret_cast<float4*>(out)[i] = o;
}

extern "C" void kernel_launch(void* const* d_in, const int* in_sizes, int n_in,
                              void* d_out, int out_size, void* d_ws, size_t ws_size,
                              hipStream_t stream) {
    const float* x      = (const float*)d_in[0];   // (4,1024,64) f32
    const float* params = (const float*)d_in[1];   // (4,10) f32
    float* out = (float*)d_out;                    // (4,1024,64) f32

    const int total4 = out_size / 4;               // 65536 float4s
    qc_fused<<<total4 / 256, 256, 0, stream>>>(x, params, out);
}